// Round 8
// baseline (202.935 us; speedup 1.0000x reference)
//
#include <hip/hip_runtime.h>
#include <cmath>
#include <cstdint>

#define TSZ 1024
#define RDIV 2.5f
#define UCONST 0.83f

typedef __bf16 bf16x8 __attribute__((ext_vector_type(8)));
typedef float f32x4 __attribute__((ext_vector_type(4)));
typedef unsigned short ushortT;

__device__ __forceinline__ ushortT bf16r(float f) {
  union { float f; unsigned u; } x; x.f = f;
  unsigned r = (x.u + 0x7FFFu + ((x.u >> 16) & 1u)) >> 16;
  return (ushortT)r;
}

__device__ __forceinline__ void glds16(const void* g, void* l) {
  __builtin_amdgcn_global_load_lds(
      (const __attribute__((address_space(1))) unsigned int*)(g),
      (__attribute__((address_space(3))) unsigned int*)(l), 16, 0, 0);
}

// nb padded layout: [16][66][66][128] bf16. strides (ushort): row 8448, n 557568.
#define NB_ROW 8448
#define NB_N 557568

// ============ k_cvtg: NCHW fp32 -> padded NHWC bf16 + 9-tap dot planes ============
__global__ __launch_bounds__(256) void k_cvtg(const float* __restrict__ in,
                                              const float* __restrict__ a,
                                              ushortT* __restrict__ nb,
                                              float* __restrict__ g,
                                              int* __restrict__ count) {
  __shared__ float tile2[128][65];
  __shared__ float gpart[4][9][64];
  const int bid = blockIdx.x;            // 1024 = 16 n * 64 y
  const int n = bid >> 6, y = bid & 63;
  const int t = threadIdx.x;
  if (t == 0) count[bid] = 0;
  {
    const int chs = t >> 4, l16 = t & 15;
    const float* basep = in + ((size_t)(n * 128) << 12) + (y << 6) + (l16 << 2);
#pragma unroll
    for (int i = 0; i < 8; ++i) {
      int ch = (i << 4) + chs;
      f32x4 v = *reinterpret_cast<const f32x4*>(basep + ((size_t)ch << 12));
#pragma unroll
      for (int u = 0; u < 4; ++u) tile2[ch][(l16 << 2) + u] = v[u];
    }
  }
  __syncthreads();
  {
    const int part = __builtin_amdgcn_readfirstlane(t >> 6);
    const int x = t & 63;
    float gacc[9];
#pragma unroll
    for (int tap = 0; tap < 9; ++tap) gacc[tap] = 0.f;
    const int c0 = part << 5;
#pragma unroll
    for (int i = 0; i < 32; ++i) {
      float v = tile2[c0 + i][x];
      const float* ap = a + (c0 + i) * 9;
#pragma unroll
      for (int tap = 0; tap < 9; ++tap) gacc[tap] += v * ap[tap];
    }
#pragma unroll
    for (int tap = 0; tap < 9; ++tap) gpart[part][tap][x] = gacc[tap];
  }
  __syncthreads();
  if (t < 64) {
    const int x = t;
#pragma unroll
    for (int tap = 0; tap < 9; ++tap) {
      float s = gpart[0][tap][x] + gpart[1][tap][x] + gpart[2][tap][x] + gpart[3][tap][x];
      g[tap * 65536 + (n << 12) + (y << 6) + x] = s;
    }
  }
  // interior nb pack (padded +1,+1)
  {
    const int x2 = t >> 2;
    ushortT* dst = nb + (size_t)n * NB_N + (size_t)(y + 1) * NB_ROW + (x2 + 1) * 128;
#pragma unroll
    for (int j = 0; j < 4; ++j) {
      int c0 = ((t & 3) << 3) + (j << 5);
      union { ushortT us[8]; uint4 v; } pk;
#pragma unroll
      for (int u = 0; u < 8; ++u) pk.us[u] = bf16r(tile2[c0 + u][x2]);
      *reinterpret_cast<uint4*>(dst + c0) = pk.v;
    }
  }
  // border zeros
  {
    const uint4 z4 = {0u, 0u, 0u, 0u};
    ushortT* rowp = nb + (size_t)n * NB_N + (size_t)(y + 1) * NB_ROW;
    if (t < 16)       *reinterpret_cast<uint4*>(rowp + t * 8) = z4;              // col 0
    else if (t < 32)  *reinterpret_cast<uint4*>(rowp + 65 * 128 + (t - 16) * 8) = z4; // col 65
    if (y == 0) {
      ushortT* r0 = nb + (size_t)n * NB_N;
      for (int i = t; i < 1056; i += 256) *reinterpret_cast<uint4*>(r0 + i * 8) = z4;
    }
    if (y == 63) {
      ushortT* r65 = nb + (size_t)n * NB_N + (size_t)65 * NB_ROW;
      for (int i = t; i < 1056; i += 256) *reinterpret_cast<uint4*>(r65 + i * 8) = z4;
    }
  }
}

// ============ k_mid: norm + vote || spin-barrier || hash + argmax + wprep ============
// 256 blocks x 256 thr, ~9 KB LDS -> all co-resident (device spin barrier safe).
__global__ __launch_bounds__(256) void k_mid(const float* __restrict__ g,
                                             const float* __restrict__ kw,
                                             const float* __restrict__ a,
                                             const float* __restrict__ bb,
                                             float* __restrict__ norms2,
                                             int* __restrict__ count,
                                             unsigned* __restrict__ bar,
                                             ushortT* __restrict__ wb,
                                             float* __restrict__ tail) {
  __shared__ float red[256];
  __shared__ float rp[256];
  __shared__ int hist[TSZ];
  __shared__ int sc[256];
  __shared__ int si[256];
  __shared__ int sBucket;
  const int o = blockIdx.x, t = threadIdx.x;

  // ---- stage A1: norm^2 of kernel row o ----
  {
    const float* row = kw + (size_t)o * 1152;
    float s = 0.f;
    for (int j = t; j < 1152; j += 256) { float v = row[j]; s += v * v; }
    red[t] = s; __syncthreads();
    for (int st = 128; st; st >>= 1) {
      if (t < st) red[t] += red[t + st];
      __syncthreads();
    }
    if (t == 0) norms2[o] = red[0];
  }
  // ---- stage A2: vote for this block's 256 pixels ----
  for (int i = t; i < TSZ; i += 256) hist[i] = 0;
  __syncthreads();
  {
    const int pix = o * 256 + t;
    const int n = pix >> 12, y = (pix >> 6) & 63, x = pix & 63;
    float acc = 0.f;
#pragma unroll
    for (int tap = 0; tap < 9; ++tap) {
      const int dy = tap / 3 - 1, dx = tap % 3 - 1;
      const int yy = y + dy, xx = x + dx;
      if ((unsigned)yy < 64u && (unsigned)xx < 64u)
        acc += g[tap * 65536 + (n << 12) + (yy << 6) + xx];
    }
    const float* av = a + 1152;
#pragma unroll
    for (int ky = 0; ky < 3; ++ky) {
      int yy = y + ky - 1;
      if ((unsigned)yy >= 64u) continue;
#pragma unroll
      for (int kx = 0; kx < 3; ++kx) {
        int xx = x + kx - 1;
        if ((unsigned)xx >= 64u) continue;
        acc += 0.5f * av[ky * 3 + kx];
      }
    }
    int v = (int)floorf((acc + bb[0]) / RDIV);
    int r = v % TSZ; if (r < 0) r = -r;
    atomicAdd(&hist[r], 1);
  }
  __syncthreads();
  for (int i = t; i < TSZ; i += 256) {
    int h = hist[i];
    if (h) atomicAdd(&count[i], h);
  }
  // ---- device-wide spin barrier (all 256 blocks co-resident) ----
  __threadfence();
  __syncthreads();
  if (t == 0) {
    __hip_atomic_fetch_add(bar, 1u, __ATOMIC_ACQ_REL, __HIP_MEMORY_SCOPE_AGENT);
    while (__hip_atomic_load(bar, __ATOMIC_ACQUIRE, __HIP_MEMORY_SCOPE_AGENT) < 256u) {
      __builtin_amdgcn_s_sleep(8);
    }
  }
  __syncthreads();
  __threadfence();
  // ---- stage B1: scale from max norm ----
  red[t] = norms2[t]; __syncthreads();
  for (int st = 128; st; st >>= 1) {
    if (t < st) red[t] = fmaxf(red[t], red[t + st]);
    __syncthreads();
  }
  const float scale = UCONST / sqrtf(red[0]);
  __syncthreads();
  // ---- stage B2: hash row o -> bucket ----
  {
    const float* row = kw + (size_t)o * 1152;
    float dot = 0.f, p = 0.f;
    for (int j = t; j < 1152; j += 256) {
      float x = row[j] * scale;
      dot += x * a[j];
      p += x * x;
    }
    red[t] = dot; rp[t] = p; __syncthreads();
    for (int st = 128; st; st >>= 1) {
      if (t < st) { red[t] += red[t + st]; rp[t] += rp[t + st]; }
      __syncthreads();
    }
    if (t == 0) {
      float acc = red[0], pw = rp[0];
      for (int i = 0; i < 9; i++) { acc += pw * a[1152 + i]; pw = pw * pw; }
      acc += bb[0];
      int hi = (int)floorf(acc / RDIV);
      int r = hi % TSZ; if (r < 0) r = -r;
      sBucket = r;
    }
  }
  // ---- stage B3: argmax over count ----
  {
    int bc = count[t], bi = t;
#pragma unroll
    for (int j = 1; j < 4; ++j) {
      int i2 = t + j * 256;
      int c2 = count[i2];
      if (c2 > bc) { bc = c2; bi = i2; }
    }
    sc[t] = bc; si[t] = bi; __syncthreads();
    for (int st = 128; st; st >>= 1) {
      if (t < st) {
        int c2 = sc[t + st], i2 = si[t + st];
        if (c2 > sc[t] || (c2 == sc[t] && i2 < si[t])) { sc[t] = c2; si[t] = i2; }
      }
      __syncthreads();
    }
  }
  const int idx = si[0];
  const int m = (sBucket == idx) ? 1 : 0;
  if (t == 0) {
    if (o == 0) tail[0] = (float)idx;
    tail[1 + o] = (float)m;
  }
  // ---- stage B4: masked bf16 weight row (k = tap*128 + c) ----
  const float mf = m ? 1.f : 0.f;
  const float* wr = kw + (size_t)o * 1152;
  ushortT* dst = wb + (size_t)o * 1152;
  for (int j = t; j < 1152; j += 256) {
    int r = j >> 7, c = j & 127;
    dst[j] = bf16r(wr[c * 9 + r] * mf);
  }
}

// ============ k_gemm5: M=65536, N=256, K=1152, padded-A, imm-offset LDS ============
// BM=256 (4 rows), BN=256, BK=32. 512 thr = 8 waves (2M x 4N), wave 128x64.
// 3 LDS bufs x 32KB. Fragment-linear LDS; K-loop unrolled x3 so every ds_read
// is base+immediate; staging = 1 uniform add per glds (padded nb, no OOB).
__global__ __launch_bounds__(512, 1) void k_gemm5(const ushortT* __restrict__ nb,
                                                  const ushortT* __restrict__ wb,
                                                  float* __restrict__ out) {
  __shared__ __align__(16) char smem[3 * 32768];
  const int t = threadIdx.x, l = t & 63, w = t >> 6;
  const int mb = blockIdx.x;               // 256 = 16 n * 16 ygroups
  const int n = mb >> 4;
  const int y0 = (mb & 15) << 2;
  const int wm = w & 1, wn = w >> 1;
  const int lr = l & 15, lq = l >> 4;

  // staging: wave w owns chunks 4w..4w+3 (w<4: A, else B)
  const char* srcBase[4];
  int lds_o[4];
  const bool isA = (w < 4);
#pragma unroll
  for (int j = 0; j < 4; ++j) {
    int c = (w << 2) + j;
    lds_o[j] = c << 10;
    if (isA) {
      int m = (c << 4) + lr;               // pixel 0..255
      int yl = m >> 6, x = m & 63;
      srcBase[j] = (const char*)nb + (size_t)n * (NB_N * 2) +
                   (size_t)(y0 + yl + 1) * (NB_ROW * 2) + (x + 1) * 256 + (lq << 4);
    } else {
      int orow = ((c - 16) << 4) + lr;
      srcBase[j] = (const char*)wb + (size_t)orow * 2304 + (lq << 4);
    }
  }

  auto srcOff = [&](int s) -> int {
    if (isA) {
      int tap = s >> 2;
      int d3 = (tap * 21846) >> 16;        // tap/3 for tap<9
      int dy = d3 - 1, dx = tap - d3 * 3 - 1;
      return dy * (NB_ROW * 2) + dx * 256 + ((s & 3) << 6);
    }
    return s << 6;
  };

  auto stage2 = [&](int buf, int s, int jlo) {
    const int off = srcOff(s);
    char* dstb = smem + buf * 32768;
#pragma unroll
    for (int j = jlo; j < jlo + 2; ++j)
      glds16(srcBase[j] + off, dstb + lds_o[j]);
  };

  f32x4 acc[8][4] = {};

  stage2(0, 0, 0); stage2(0, 0, 2);
  stage2(1, 1, 0); stage2(1, 1, 2);
  asm volatile("s_waitcnt vmcnt(4)" ::: "memory");
  __builtin_amdgcn_s_barrier();

  const char* lA = smem + (wm << 13) + (l << 4);           // A frag mi -> +mi*1024
  const char* lB = smem + 16384 + (wn << 12) + (l << 4);   // B frag ni -> +ni*1024

  for (int big = 0; big < 12; ++big) {
#pragma unroll
    for (int u = 0; u < 3; ++u) {
      const int tt = big * 3 + u;          // tt % 3 == u
      const bool stg = tt < 34;
      const int ss = tt + 2;
      const int sb = (u + 2) % 3;          // compile-time per u
      bf16x8 bv[4], afA[4], afB[4];
      // ---- phase 0: B frags + A lower ----
#pragma unroll
      for (int ni = 0; ni < 4; ++ni)
        bv[ni] = *reinterpret_cast<const bf16x8*>(lB + u * 32768 + (ni << 10));
#pragma unroll
      for (int mi = 0; mi < 4; ++mi)
        afA[mi] = *reinterpret_cast<const bf16x8*>(lA + u * 32768 + (mi << 10));
      if (stg) stage2(sb, ss, 0);
      __builtin_amdgcn_s_barrier();
      __builtin_amdgcn_s_setprio(1);
#pragma unroll
      for (int mi = 0; mi < 4; ++mi)
#pragma unroll
        for (int ni = 0; ni < 4; ++ni)
          acc[mi][ni] = __builtin_amdgcn_mfma_f32_16x16x32_bf16(
              afA[mi], bv[ni], acc[mi][ni], 0, 0, 0);
      __builtin_amdgcn_s_setprio(0);
      __builtin_amdgcn_s_barrier();
      // ---- phase 1: A upper (B reused in regs) ----
#pragma unroll
      for (int mi = 0; mi < 4; ++mi)
        afB[mi] = *reinterpret_cast<const bf16x8*>(lA + u * 32768 + ((4 + mi) << 10));
      if (stg) stage2(sb, ss, 2);
      __builtin_amdgcn_s_barrier();
      __builtin_amdgcn_s_setprio(1);
#pragma unroll
      for (int mi = 0; mi < 4; ++mi)
#pragma unroll
        for (int ni = 0; ni < 4; ++ni)
          acc[4 + mi][ni] = __builtin_amdgcn_mfma_f32_16x16x32_bf16(
              afB[mi], bv[ni], acc[4 + mi][ni], 0, 0, 0);
      __builtin_amdgcn_s_setprio(0);
      if (tt == 34)     asm volatile("s_waitcnt vmcnt(0)" ::: "memory");
      else if (tt < 34) asm volatile("s_waitcnt vmcnt(4)" ::: "memory");
      if (tt < 35) __builtin_amdgcn_s_barrier();
    }
  }

  // epilogue: col o = wn*64+ni*16+lr, row m = wm*128+mi*16+lq*4+reg (contig x)
  const int pos0 = (mb & 15) << 8;
#pragma unroll
  for (int ni = 0; ni < 4; ++ni) {
    const int o = (wn << 6) + (ni << 4) + lr;
    float* op = out + ((size_t)((n << 8) + o) << 12) + pos0 + (wm << 7) + (lq << 2);
#pragma unroll
    for (int mi = 0; mi < 8; ++mi)
      *reinterpret_cast<f32x4*>(op + (mi << 4)) = acc[mi][ni];
  }
}

// ============ SMALL-tier fallback kernels (known-good) ============
__global__ __launch_bounds__(256) void k_norm(const float* __restrict__ k,
                                              unsigned* __restrict__ scaleBits) {
  int o = blockIdx.x;
  const float* row = k + (size_t)o * 1152;
  float s = 0.f;
  for (int j = threadIdx.x; j < 1152; j += 256) { float v = row[j]; s += v * v; }
  __shared__ float red[256];
  red[threadIdx.x] = s; __syncthreads();
  for (int st = 128; st; st >>= 1) {
    if (threadIdx.x < st) red[threadIdx.x] += red[threadIdx.x + st];
    __syncthreads();
  }
  if (threadIdx.x == 0) atomicMax(scaleBits, __float_as_uint(red[0]));
}

__global__ __launch_bounds__(256) void k_hash(const float* __restrict__ k,
                                              const float* __restrict__ a,
                                              const float* __restrict__ b,
                                              const unsigned* __restrict__ scaleBits,
                                              int* __restrict__ bucket) {
  int o = blockIdx.x;
  float scale = UCONST / sqrtf(__uint_as_float(scaleBits[0]));
  const float* row = k + (size_t)o * 1152;
  float dot = 0.f, p = 0.f;
  for (int j = threadIdx.x; j < 1152; j += 256) {
    float x = row[j] * scale;
    dot += x * a[j];
    p += x * x;
  }
  __shared__ float rd[256], rp[256];
  rd[threadIdx.x] = dot; rp[threadIdx.x] = p; __syncthreads();
  for (int st = 128; st; st >>= 1) {
    if (threadIdx.x < st) { rd[threadIdx.x] += rd[threadIdx.x + st]; rp[threadIdx.x] += rp[threadIdx.x + st]; }
    __syncthreads();
  }
  if (threadIdx.x == 0) {
    float acc = rd[0];
    float pw = rp[0];
    for (int i = 0; i < 9; i++) { acc += pw * a[1152 + i]; pw = pw * pw; }
    acc += b[0];
    float h = floorf(acc / RDIV);
    int hi = (int)h;
    int r = hi % TSZ; if (r < 0) r = -r;
    bucket[o] = r;
  }
}

__global__ __launch_bounds__(256) void k_vote2(const float* __restrict__ in,
                                               const float* __restrict__ a,
                                               const float* __restrict__ bb,
                                               int* __restrict__ count) {
  __shared__ float sb[6][8][64];
  __shared__ int hist[TSZ];
  const int t = threadIdx.x;
  for (int i = t; i < TSZ; i += 256) hist[i] = 0;
  const int bid = blockIdx.x;
  const int n = bid >> 4, y0 = (bid & 15) << 2;
  const int x = t & 63, ry = t >> 6;
  const int yq = y0 + ry;
  float acc = 0.f;
  const float* base = in + (size_t)n * 524288;
  for (int cc = 0; cc < 16; ++cc) {
    __syncthreads();
#pragma unroll
    for (int k = 0; k < 12; ++k) {
      int i = k * 256 + t;
      int row = i >> 9;
      int c8 = (i >> 6) & 7;
      int xx = i & 63;
      int yy = y0 - 1 + row;
      float v = 0.f;
      if ((unsigned)yy < 64u) v = base[(size_t)(cc * 8 + c8) * 4096 + yy * 64 + xx];
      sb[row][c8][xx] = v;
    }
    __syncthreads();
#pragma unroll
    for (int c8 = 0; c8 < 8; ++c8) {
      const float* av = a + (cc * 8 + c8) * 9;
#pragma unroll
      for (int ky = 0; ky < 3; ++ky) {
        const float* rowp = sb[ry + ky][c8];
        float left  = (x >= 1)  ? rowp[x - 1] : 0.f;
        float mid   = rowp[x];
        float right = (x <= 62) ? rowp[x + 1] : 0.f;
        acc += left * av[ky * 3 + 0] + mid * av[ky * 3 + 1] + right * av[ky * 3 + 2];
      }
    }
  }
  {
    const float* av = a + 1152;
#pragma unroll
    for (int ky = 0; ky < 3; ++ky) {
      int yy = yq + ky - 1;
      if ((unsigned)yy >= 64u) continue;
#pragma unroll
      for (int kx = 0; kx < 3; ++kx) {
        int xx = x + kx - 1;
        if ((unsigned)xx >= 64u) continue;
        acc += 0.5f * av[ky * 3 + kx];
      }
    }
  }
  int v = (int)floorf((acc + bb[0]) / RDIV);
  int r = v % TSZ; if (r < 0) r = -r;
  atomicAdd(&hist[r], 1);
  __syncthreads();
  for (int i = t; i < TSZ; i += 256) {
    int h = hist[i];
    if (h) atomicAdd(&count[i], h);
  }
}

__global__ __launch_bounds__(1024) void k_argmax(const int* __restrict__ count,
                                                 const int* __restrict__ bucket,
                                                 int* __restrict__ maskI,
                                                 float* __restrict__ tail) {
  __shared__ int sc[1024];
  __shared__ int si[1024];
  int t = threadIdx.x;
  sc[t] = count[t]; si[t] = t; __syncthreads();
  for (int st = 512; st; st >>= 1) {
    if (t < st) {
      int c2 = sc[t + st], i2 = si[t + st];
      if (c2 > sc[t] || (c2 == sc[t] && i2 < si[t])) { sc[t] = c2; si[t] = i2; }
    }
    __syncthreads();
  }
  int idx = si[0];
  if (t == 0) tail[0] = (float)idx;
  if (t < 256) {
    int m = (bucket[t] == idx) ? 1 : 0;
    maskI[t] = m;
    tail[1 + t] = (float)m;
  }
}

__global__ __launch_bounds__(256) void k_conv(const float* __restrict__ in,
                                              const float* __restrict__ w,
                                              const int* __restrict__ maskI,
                                              float* __restrict__ out) {
  const int og = blockIdx.x, n = blockIdx.y, yt = blockIdx.z;
  const int tid = threadIdx.x;
  const int tx = tid & 63, trow = tid >> 6;
  const int y0 = yt * 4;
  const int oc0 = og * 4;
  const int m0 = maskI[oc0], m1 = maskI[oc0 + 1], m2 = maskI[oc0 + 2], m3 = maskI[oc0 + 3];
  float* op = out + ((size_t)(n * 256 + oc0)) * 4096 + (size_t)(y0 + trow) * 64 + tx;
  if (!(m0 | m1 | m2 | m3)) {
    op[0] = 0.f; op[4096] = 0.f; op[8192] = 0.f; op[12288] = 0.f;
    return;
  }
  __shared__ float tile[6 * 66];
  const float* base = in + (size_t)n * 128 * 4096;
  const float* wb = w + (size_t)oc0 * 1152;
  float a0 = 0.f, a1 = 0.f, a2 = 0.f, a3 = 0.f;
  for (int c = 0; c < 128; c++) {
    __syncthreads();
    for (int i = tid; i < 396; i += 256) {
      int r = i / 66, col = i - r * 66;
      int yy = y0 - 1 + r, xx = col - 1;
      float v = 0.f;
      if ((unsigned)yy < 64u && (unsigned)xx < 64u) v = base[(size_t)c * 4096 + yy * 64 + xx];
      tile[i] = v;
    }
    __syncthreads();
    const int ro = trow * 66 + tx;
    float t00 = tile[ro],        t01 = tile[ro + 1],   t02 = tile[ro + 2];
    float t10 = tile[ro + 66],   t11 = tile[ro + 67],  t12 = tile[ro + 68];
    float t20 = tile[ro + 132],  t21 = tile[ro + 133], t22 = tile[ro + 134];
    const float* wc = wb + c * 9;
    if (m0) { const float* q = wc;        a0 += t00*q[0]+t01*q[1]+t02*q[2]+t10*q[3]+t11*q[4]+t12*q[5]+t20*q[6]+t21*q[7]+t22*q[8]; }
    if (m1) { const float* q = wc + 1152; a1 += t00*q[0]+t01*q[1]+t02*q[2]+t10*q[3]+t11*q[4]+t12*q[5]+t20*q[6]+t21*q[7]+t22*q[8]; }
    if (m2) { const float* q = wc + 2304; a2 += t00*q[0]+t01*q[1]+t02*q[2]+t10*q[3]+t11*q[4]+t12*q[5]+t20*q[6]+t21*q[7]+t22*q[8]; }
    if (m3) { const float* q = wc + 3456; a3 += t00*q[0]+t01*q[1]+t02*q[2]+t10*q[3]+t11*q[4]+t12*q[5]+t20*q[6]+t21*q[7]+t22*q[8]; }
  }
  op[0]     = m0 ? a0 : 0.f;
  op[4096]  = m1 ? a1 : 0.f;
  op[8192]  = m2 ? a2 : 0.f;
  op[12288] = m3 ? a3 : 0.f;
}

extern "C" void kernel_launch(void* const* d_in, const int* in_sizes, int n_in,
                              void* d_out, int out_size, void* d_ws, size_t ws_size,
                              hipStream_t stream) {
  const float* in = (const float*)d_in[0];   // [16,128,64,64]
  const float* kw = (const float*)d_in[1];   // [256,128,3,3]
  const float* a  = (const float*)d_in[2];   // [1161]
  const float* b  = (const float*)d_in[3];   // [1]
  float* out = (float*)d_out;                // 16777216 + 1 + 256 floats

  char* ws = (char*)d_ws;
  // fast-path ws layout
  const size_t OFF_WB    = 17842176ULL;      // nb padded: 16*66*66*128*2
  const size_t OFF_COUNT = 18432000ULL;      // wb: 589824
  const size_t OFF_NORM  = 18436096ULL;      // count: 4096
  const size_t OFF_BAR   = 18437120ULL;      // norms2: 1024
  const size_t NEED_BIG  = 18437184ULL;      // bar: 64

  if (ws_size >= NEED_BIG) {
    ushortT* nb    = (ushortT*)(ws);
    ushortT* wb    = (ushortT*)(ws + OFF_WB);
    int* count     = (int*)(ws + OFF_COUNT);
    float* norms2  = (float*)(ws + OFF_NORM);
    unsigned* bar  = (unsigned*)(ws + OFF_BAR);
    float* g       = out;                    // aliases out[0..589824) — overwritten by gemm later

    hipMemsetAsync(bar, 0, 64, stream);
    k_cvtg<<<1024, 256, 0, stream>>>(in, a, nb, g, count);
    k_mid<<<256, 256, 0, stream>>>(g, kw, a, b, norms2, count, bar, wb, out + 16777216);
    k_gemm5<<<256, 512, 0, stream>>>(nb, wb, out);
  } else {
    // -------- fallback: direct conv path (known-good) --------
    int* count    = (int*)(ws);
    unsigned* scB = (unsigned*)(ws + 4096);
    int* bucket   = (int*)(ws + 4160);
    int* maskI    = (int*)(ws + 5184);

    hipMemsetAsync(ws, 0, 4160, stream);
    k_norm<<<256, 256, 0, stream>>>(kw, scB);
    k_hash<<<256, 256, 0, stream>>>(kw, a, b, scB, bucket);
    k_vote2<<<256, 256, 0, stream>>>(in, a, b, count);
    k_argmax<<<1, 1024, 0, stream>>>(count, bucket, maskI, out + 16777216);
    dim3 grid(64, 16, 16);
    k_conv<<<grid, 256, 0, stream>>>(in, kw, maskI, out);
  }
}